// Round 3
// baseline (327.758 us; speedup 1.0000x reference)
//
#include <hip/hip_runtime.h>

// DisplaceChannel v3: stage displaced+masked plane into LDS (guard ring of
// zeros = conv padding), then mask-free separable 3x3 Gaussian from LDS.
// B=32, C=384 (48 pos x 8 ch), H=W=64, K=3, SIGMA=0.5.

constexpr int HH = 64;
constexpr int WW = 64;
constexpr int B_ = 32;
constexpr int C_ = 384;
constexpr int PLANES = B_ * C_;                    // 12288
constexpr long long NELEM = (long long)PLANES * HH * WW;
constexpr int LSTR = 76;   // LDS row stride (floats): %4==0 -> 16B-aligned row
                           // starts; mod 32 = 12 -> conflict-free b128 writes
constexpr int GL = 3;      // read window for out-col x4 starts at lds col GL+x4
                           // (col 3 = x=-1 guard; data cols 4..67; col 68 = x=64)

__global__ __launch_bounds__(256) void displace_conv_v3(
    const float* __restrict__ inp, const float* __restrict__ offset,
    float* __restrict__ out) {
  __shared__ float lds[66 * LSTR];                 // 66 rows (1+64+1 guards)

  const int plane = blockIdx.x;                    // [0, 12288)
  const int c = plane % C_;
  const int pos = c >> 3;                          // 8 channels per position

  const float offx = offset[2 * pos + 0];
  const float offy = offset[2 * pos + 1];
  const float rx = rintf(offx);                    // matches jnp.round
  const float ry = rintf(offy);
  const int ox = (int)rx;
  const int oy = (int)ry;
  const float fx = offx - rx;
  const float fy = offy - ry;

  // Separable Gaussian taps, normalized so (sum gx)*(sum gy) = full 3x3 sum.
  float gx0 = __expf(-2.f * (fx - 1.f) * (fx - 1.f));
  float gx1 = __expf(-2.f * fx * fx);
  float gx2 = __expf(-2.f * (fx + 1.f) * (fx + 1.f));
  const float sxi = 1.f / (gx0 + gx1 + gx2);
  gx0 *= sxi; gx1 *= sxi; gx2 *= sxi;

  float gy0 = __expf(-2.f * (fy - 1.f) * (fy - 1.f));
  float gy1 = __expf(-2.f * fy * fy);
  float gy2 = __expf(-2.f * (fy + 1.f) * (fy + 1.f));
  const float syi = 1.f / (gy0 + gy1 + gy2);
  gy0 *= syi; gy1 *= syi; gy2 *= syi;

  const int t = threadIdx.x;

  // --- zero the guard ring ---
  if (t < LSTR) {
    lds[t] = 0.f;                                  // row y=-1
    lds[65 * LSTR + t] = 0.f;                      // row y=64
  }
  if (t < 64) {
    lds[(t + 1) * LSTR + 3] = 0.f;                 // col x=-1
    lds[(t + 1) * LSTR + 68] = 0.f;                // col x=64
  }

  // --- stage displaced image (zeros where displaced-out) ---
  {
    const int r = t >> 2;                          // dest row 0..63
    const int d0 = (t & 3) << 4;                   // dest col group: 16 cols
    const bool rowok = (unsigned)(r - oy) < (unsigned)HH;
    int rc = r - oy;
    rc = rc < 0 ? 0 : (rc > HH - 1 ? HH - 1 : rc);
    const float* p = inp + (size_t)plane * (HH * WW) + rc * WW + (d0 - ox);
    const float* const lo = inp;
    const float* const hi = inp + (NELEM - 16);
    p = p < lo ? lo : (p > hi ? hi : p);           // safety; never triggers
    float s[16];
    __builtin_memcpy(&s[0], p, 16);                // 4x align-4 dwordx4
    __builtin_memcpy(&s[4], p + 4, 16);
    __builtin_memcpy(&s[8], p + 8, 16);
    __builtin_memcpy(&s[12], p + 12, 16);
    float v[16];
#pragma unroll
    for (int j = 0; j < 16; ++j) {
      const bool ok = rowok && ((unsigned)(d0 + j - ox) < (unsigned)WW);
      v[j] = ok ? s[j] : 0.f;                      // select (NaN-safe)
    }
    float* dst = &lds[(r + 1) * LSTR + 4 + d0];    // 16B-aligned
#pragma unroll
    for (int j = 0; j < 4; ++j)
      *(float4*)(dst + 4 * j) =
          make_float4(v[4 * j], v[4 * j + 1], v[4 * j + 2], v[4 * j + 3]);
  }

  __syncthreads();

  // --- mask-free separable conv out of LDS ---
  const int x4 = (t & 15) << 2;                    // output cols x4..x4+3
  const int y0 = (t >> 4) << 2;                    // output rows y0..y0+3
  float* __restrict__ obase = out + (size_t)plane * (HH * WW);

  auto hrow = [&](int ty) -> float4 {
    const float* p = &lds[(ty + 1) * LSTR + GL + x4];
    float4 r;
    r.x = gx0 * p[0] + gx1 * p[1] + gx2 * p[2];
    r.y = gx0 * p[1] + gx1 * p[2] + gx2 * p[3];
    r.z = gx0 * p[2] + gx1 * p[3] + gx2 * p[4];
    r.w = gx0 * p[3] + gx1 * p[4] + gx2 * p[5];
    return r;
  };

  float4 a = hrow(y0 - 1);
  float4 b = hrow(y0);
#pragma unroll
  for (int i = 0; i < 4; ++i) {
    const float4 cc = hrow(y0 + 1 + i);
    float4 o;
    o.x = gy0 * a.x + gy1 * b.x + gy2 * cc.x;
    o.y = gy0 * a.y + gy1 * b.y + gy2 * cc.y;
    o.z = gy0 * a.z + gy1 * b.z + gy2 * cc.z;
    o.w = gy0 * a.w + gy1 * b.w + gy2 * cc.w;
    *(float4*)(obase + (y0 + i) * WW + x4) = o;    // aligned 16B store
    a = b;
    b = cc;
  }
}

extern "C" void kernel_launch(void* const* d_in, const int* in_sizes, int n_in,
                              void* d_out, int out_size, void* d_ws, size_t ws_size,
                              hipStream_t stream) {
  const float* inp = (const float*)d_in[0];
  const float* offset = (const float*)d_in[1];
  float* out = (float*)d_out;
  displace_conv_v3<<<PLANES, 256, 0, stream>>>(inp, offset, out);
}